// Round 1
// baseline (149.806 us; speedup 1.0000x reference)
//
#include <hip/hip_runtime.h>

// TensorProduct: N=100000, C=128
// x1: (N, 512) = [s1 (128) | v1 (128x3 interleaved)]
// x2: (N, 4)   = [s2 | v2 (3)]
// w : (N, 640) = 5 paths x 128 channels
// out: (N, 896) = [out_s (128) | out_vo (128x3) | out_ve (128x3)]

#define C 128

__device__ __constant__ float kInvSqrt2 = 0.70710678118654752440f;
__device__ __constant__ float kInvSqrt3 = 0.57735026918962576451f;

__global__ void __launch_bounds__(256) TensorProduct_86397562126686_kernel(
    const float* __restrict__ x1,
    const float* __restrict__ x2,
    const float* __restrict__ w,
    float* __restrict__ out,
    int N)
{
    int tid = blockIdx.x * blockDim.x + threadIdx.x;
    int total = N * C;
    if (tid >= total) return;

    int n = tid >> 7;        // row
    int c = tid & (C - 1);   // channel

    const float* __restrict__ x1r = x1 + (size_t)n * (4 * C);
    const float* __restrict__ wr  = w  + (size_t)n * (5 * C);

    // x2 row: same address for all 128 lanes of this row -> broadcast fetch
    float4 x2v = *reinterpret_cast<const float4*>(x2 + (size_t)n * 4);
    float s2  = x2v.x;
    float v2x = x2v.y;
    float v2y = x2v.z;
    float v2z = x2v.w;

    float s1 = x1r[c];
    const float* __restrict__ v1p = x1r + C + 3 * c;
    float a0 = v1p[0];
    float a1 = v1p[1];
    float a2 = v1p[2];

    float w0 = wr[0 * C + c];
    float w1 = wr[1 * C + c];
    float w2 = wr[2 * C + c];
    float w3 = wr[3 * C + c];
    float w4 = wr[4 * C + c];

    const float pw2 = kInvSqrt2;

    // out_s
    float dot  = a0 * v2x + a1 * v2y + a2 * v2z;
    float outs = pw2 * (w0 * s1 * s2 + w1 * kInvSqrt3 * dot);

    // out_vo
    float vo0 = pw2 * (w2 * s1 * v2x + w3 * a0 * s2);
    float vo1 = pw2 * (w2 * s1 * v2y + w3 * a1 * s2);
    float vo2 = pw2 * (w2 * s1 * v2z + w3 * a2 * s2);

    // out_ve = pw2 * w4 * (v1 x v2)
    float cx = a1 * v2z - a2 * v2y;
    float cy = a2 * v2x - a0 * v2z;
    float cz = a0 * v2y - a1 * v2x;
    float ve0 = pw2 * w4 * cx;
    float ve1 = pw2 * w4 * cy;
    float ve2 = pw2 * w4 * cz;

    float* __restrict__ outr = out + (size_t)n * 896;
    outr[c] = outs;

    float* __restrict__ vop = outr + C + 3 * c;
    vop[0] = vo0;
    vop[1] = vo1;
    vop[2] = vo2;

    float* __restrict__ vep = outr + 4 * C + 3 * c;
    vep[0] = ve0;
    vep[1] = ve1;
    vep[2] = ve2;
}

extern "C" void kernel_launch(void* const* d_in, const int* in_sizes, int n_in,
                              void* d_out, int out_size, void* d_ws, size_t ws_size,
                              hipStream_t stream) {
    const float* x1 = (const float*)d_in[0];
    const float* x2 = (const float*)d_in[1];
    const float* w  = (const float*)d_in[2];
    float* out = (float*)d_out;

    int N = in_sizes[0] / (4 * C);   // 100000
    int total = N * C;               // 12.8M threads
    int block = 256;
    int grid = (total + block - 1) / block;

    TensorProduct_86397562126686_kernel<<<grid, block, 0, stream>>>(x1, x2, w, out, N);
}